// Round 11
// baseline (7161.156 us; speedup 1.0000x reference)
//
#include <hip/hip_runtime.h>
#include <math.h>

// Matrix-Tree marginals: probs[b,i,j] = A[i,j]*(X[i-1,i-1] - (j>=1 ? X[j-1,i-1] : 0))
// X = inv(M) via blocked in-place Gauss-Jordan (4 panel steps of 64, SDD -> no pivoting).
// Round-11: round-8 fused k_step (best measured: 570us total) + full T14 register prestage.
// All global reads consumed by phase 2 (R_old) and phase 3 (F panel) are issued at kernel
// start into static register arrays; their latency drains under the serial GJ chain.
// Hot loops touch LDS only. (R10's column-split regressed: +86% traffic, dup GJ.)
// ws (doubles): M[B][256][256] | mb[B] | nb[B](int) | Dg[B][256]; partial aliases Dg.

#define S 256
#define BB 256

__device__ __forceinline__ int rowmap(int lr, int kb) {   // local 0..191 -> global row skipping panel kb
    int rt = lr >> 6;
    int rb = rt + (rt >= kb ? 1 : 0);
    return rb * 64 + (lr & 63);
}

// ---------------- kernel 1a: dense max over each batch's full 256x256 score matrix ----------
__global__ __launch_bounds__(256) void k_max(const float* __restrict__ sc,
                                             float* __restrict__ partial) {
    int b = blockIdx.y, rg = blockIdx.x;                 // 8 row-groups of 32 rows
    const float4* p4 = (const float4*)(sc + (size_t)b * S * S + rg * 8192);
    int tid = threadIdx.x;
    float4 v[8];
    #pragma unroll
    for (int it = 0; it < 8; ++it) v[it] = p4[tid + 256 * it];
    float m = -1e30f;
    #pragma unroll
    for (int it = 0; it < 8; ++it)
        m = fmaxf(m, fmaxf(fmaxf(v[it].x, v[it].y), fmaxf(v[it].z, v[it].w)));
    for (int off = 32; off > 0; off >>= 1) m = fmaxf(m, __shfl_down(m, off));
    __shared__ float sm[4];
    if ((tid & 63) == 0) sm[tid >> 6] = m;
    __syncthreads();
    if (tid == 0) partial[b * 8 + rg] = fmaxf(fmaxf(sm[0], sm[1]), fmaxf(sm[2], sm[3]));
}

// ---------------- kernel 1b: per-batch n (mask count) + combine partial maxima --------------
__global__ void k_n(const unsigned char* __restrict__ mk, const float* __restrict__ partial,
                    double* __restrict__ mb, int* __restrict__ nb) {
    int b = blockIdx.x, j = threadIdx.x;
    __shared__ int shc[4];

    const unsigned int* mw = (const unsigned int*)mk;    // sniff mask dtype
    unsigned int w0 = mw[0], w1 = mw[1];
    int mode = (w0 != 0u) ? 0 : ((w1 != 0u) ? 1 : 2);

    int c;
    if (mode == 0)      c = (mk[(size_t)b * S + j] != 0);
    else if (mode == 1) c = (((const int*)mk)[(size_t)b * S + j] != 0);
    else                c = (((const long long*)mk)[(size_t)b * S + j] != 0LL);

    int lane = j & 63, wid = j >> 6;
    int cs = c;
    for (int off = 32; off > 0; off >>= 1) cs += __shfl_down(cs, off);
    if (lane == 0) shc[wid] = cs;
    __syncthreads();
    if (j == 0) {
        nb[b] = shc[0] + shc[1] + shc[2] + shc[3];
        float mm = partial[b * 8];
        #pragma unroll
        for (int q = 1; q < 8; ++q) mm = fmaxf(mm, partial[b * 8 + q]);
        mb[b] = (double)mm;
    }
}

// ---------------- kernel 2: build padded M (f64, expf), 4 rows per block --------------------
__global__ __launch_bounds__(256) void k_build(const float* __restrict__ sc,
                                               const double* __restrict__ mb,
                                               const int* __restrict__ nb,
                                               double* __restrict__ Mg) {
    int b = blockIdx.y;
    int wid = threadIdx.x >> 6, lane = threadIdx.x & 63;
    int p = blockIdx.x * 4 + wid;
    int n = nb[b];
    double m = mb[b];
    __shared__ double se[4][260];
    double* Mrow = Mg + ((size_t)b * S + p) * S;
    bool act = (p < n);
    double ssum = 0.0;
    #pragma unroll
    for (int c4 = 0; c4 < 4; ++c4) {
        int j = lane + 64 * c4;
        double ev = 0.0;
        if (act && j <= n)
            ev = (double)expf((float)((double)sc[((size_t)b * S + (p + 1)) * S + j] - m));
        se[wid][j] = ev;
        ssum += ev;
    }
    for (int off = 32; off > 0; off >>= 1) ssum += __shfl_down(ssum, off);
    ssum = __shfl(ssum, 0);
    __syncthreads();                       // uniform: all 4 waves reach it
    #pragma unroll
    for (int c4 = 0; c4 < 4; ++c4) {
        int j = lane + 64 * c4;
        double v;
        if (act && j < n) v = ((j == p) ? ssum : 0.0) - se[wid][j + 1];
        else              v = (j == p) ? 1.0 : 0.0;
        Mrow[j] = v;
    }
}

// ---------------- kernel 3: fused panel step (GJ + rowG + interior + colP), T14 prestage ----
__global__ __launch_bounds__(512, 2) void k_step(double* __restrict__ Mg, int kb) {
    int b = blockIdx.x;
    double* M = Mg + (size_t)b * S * S;
    int tid = threadIdx.x;
    __shared__ double H[64 * 256];     // [G | Pinv] by GLOBAL column index, rows = pivot rows
    __shared__ double SCR[3104];       // union: GJ bufs (256) | PT(512)+Rc(1536) | FT 16x194(3104)

    int i = tid >> 3, g = tid & 7, c0 = g << 3;   // row i, col group g (8 cols)

    // ---- T14 prestage: issue ALL global reads for phases 1-3 up front ----
    // (a) diag block row fragment (phase 1)
    double c[8];
    {
        const double* src = M + (size_t)(kb * 64 + i) * S + kb * 64 + c0;
        #pragma unroll
        for (int m2 = 0; m2 < 4; ++m2) {
            double2 t = *(const double2*)(src + 2 * m2);
            c[2 * m2] = t.x; c[2 * m2 + 1] = t.y;
        }
    }
    // (b) R_old: pivot rows x non-pivot cols (phase 2). Disjoint from everything GJ touches.
    double rst[24];
    #pragma unroll
    for (int cs = 0; cs < 8; ++cs) {
        #pragma unroll
        for (int rep = 0; rep < 3; ++rep) {
            int idx = rep * 512 + tid;
            int sL = idx / 192, jj = idx - sL * 192;
            rst[cs * 3 + rep] = M[(size_t)(kb * 64 + cs * 8 + sL) * S + rowmap(jj, kb)];
        }
    }
    // (c) F panel: non-pivot rows x pivot cols (phase 3). Stable until phase-3 epilogue.
    double fst[24];
    #pragma unroll
    for (int hc = 0; hc < 8; ++hc) {          // hc = half*4 + ck
        #pragma unroll
        for (int rep = 0; rep < 3; ++rep) {
            int idx = rep * 512 + tid;
            int kk = idx & 15, lr = idx >> 4;  // lr 0..95
            fst[hc * 3 + rep] =
                M[(size_t)rowmap((hc >> 2) * 96 + lr, kb) * S + kb * 64 + (hc & 3) * 16 + kk];
        }
    }

    // ---- phase 1: register GJ on the 64x64 diag block ----
    double* rbuf = SCR;          // [2][64]
    double* cbuf = SCR + 128;    // [2][64]
    if (i == 0) {
        #pragma unroll
        for (int u = 0; u < 8; ++u) rbuf[c0 + u] = c[u];
    }
    if (g == 0) cbuf[i] = c[0];
    for (int k = 0; k < 64; ++k) {
        int par = k & 1;
        __syncthreads();
        double pv = rbuf[par * 64 + k];
        double f  = cbuf[par * 64 + i];
        double rk[8];
        #pragma unroll
        for (int m2 = 0; m2 < 4; ++m2) {
            double2 t = *(const double2*)&rbuf[par * 64 + c0 + 2 * m2];
            rk[2 * m2] = t.x; rk[2 * m2 + 1] = t.y;
        }
        double pivinv = 1.0 / pv;
        int kg = k >> 3, ks = k & 7;
        if (i == k) {
            #pragma unroll
            for (int u = 0; u < 8; ++u)
                c[u] = ((g == kg) && (u == ks)) ? pivinv : c[u] * pivinv;
        } else {
            double gm = f * pivinv;
            #pragma unroll
            for (int u = 0; u < 8; ++u)
                c[u] = ((g == kg) && (u == ks)) ? (-gm) : fma(-gm, rk[u], c[u]);
        }
        int k1 = k + 1;
        if (k1 < 64) {
            if (i == k1) {
                #pragma unroll
                for (int u = 0; u < 8; ++u) rbuf[(par ^ 1) * 64 + c0 + u] = c[u];
            }
            if (g == (k1 >> 3)) cbuf[(par ^ 1) * 64 + i] = c[k1 & 7];
        }
    }
    __syncthreads();   // GJ done; SCR reusable. Threads hold Pinv[i][c0..c0+7] in c[].

    // ---- phase 2: G = Pinv * R_old  (8 chunks of 8 k-rows, R from registers), G+Pinv -> H --
    int tx = tid & 31, ty = tid >> 5;    // ty 0..15
    double* PT = SCR;                    // PT[sL][t] = Pinv[t][cs*8+sL]   [8][64]
    double* Rc = SCR + 512;              // Rc[sL][j] = R_old[cs*8+sL][j]  [8][192]
    double2 ga[4][3];
    #pragma unroll
    for (int r = 0; r < 4; ++r)
        #pragma unroll
        for (int q = 0; q < 3; ++q) ga[r][q] = double2{0.0, 0.0};

    #pragma unroll
    for (int cs = 0; cs < 8; ++cs) {
        if (g == cs) {
            #pragma unroll
            for (int u = 0; u < 8; ++u) PT[u * 64 + i] = c[u];
        }
        #pragma unroll
        for (int rep = 0; rep < 3; ++rep) {
            int idx = rep * 512 + tid;
            int sL = idx / 192, jj = idx - sL * 192;
            Rc[sL * 192 + jj] = rst[cs * 3 + rep];
        }
        __syncthreads();
        #pragma unroll
        for (int sL = 0; sL < 8; ++sL) {
            double2 p01 = *(const double2*)&PT[sL * 64 + 4 * ty];
            double2 p23 = *(const double2*)&PT[sL * 64 + 4 * ty + 2];
            double2 r0 = *(const double2*)&Rc[sL * 192 + 2 * tx];
            double2 r1 = *(const double2*)&Rc[sL * 192 + 2 * tx + 64];
            double2 r2 = *(const double2*)&Rc[sL * 192 + 2 * tx + 128];
            ga[0][0].x = fma(p01.x, r0.x, ga[0][0].x); ga[0][0].y = fma(p01.x, r0.y, ga[0][0].y);
            ga[0][1].x = fma(p01.x, r1.x, ga[0][1].x); ga[0][1].y = fma(p01.x, r1.y, ga[0][1].y);
            ga[0][2].x = fma(p01.x, r2.x, ga[0][2].x); ga[0][2].y = fma(p01.x, r2.y, ga[0][2].y);
            ga[1][0].x = fma(p01.y, r0.x, ga[1][0].x); ga[1][0].y = fma(p01.y, r0.y, ga[1][0].y);
            ga[1][1].x = fma(p01.y, r1.x, ga[1][1].x); ga[1][1].y = fma(p01.y, r1.y, ga[1][1].y);
            ga[1][2].x = fma(p01.y, r2.x, ga[1][2].x); ga[1][2].y = fma(p01.y, r2.y, ga[1][2].y);
            ga[2][0].x = fma(p23.x, r0.x, ga[2][0].x); ga[2][0].y = fma(p23.x, r0.y, ga[2][0].y);
            ga[2][1].x = fma(p23.x, r1.x, ga[2][1].x); ga[2][1].y = fma(p23.x, r1.y, ga[2][1].y);
            ga[2][2].x = fma(p23.x, r2.x, ga[2][2].x); ga[2][2].y = fma(p23.x, r2.y, ga[2][2].y);
            ga[3][0].x = fma(p23.y, r0.x, ga[3][0].x); ga[3][0].y = fma(p23.y, r0.y, ga[3][0].y);
            ga[3][1].x = fma(p23.y, r1.x, ga[3][1].x); ga[3][1].y = fma(p23.y, r1.y, ga[3][1].y);
            ga[3][2].x = fma(p23.y, r2.x, ga[3][2].x); ga[3][2].y = fma(p23.y, r2.y, ga[3][2].y);
        }
        __syncthreads();                 // inner reads done before next chunk restages SCR
    }
    // G -> H (global-column indexing), Pinv -> H pivot cols
    #pragma unroll
    for (int r = 0; r < 4; ++r)
        #pragma unroll
        for (int q = 0; q < 3; ++q) {
            int col = rowmap(2 * tx + 64 * q, kb);
            *(double2*)&H[(4 * ty + r) * 256 + col] = ga[r][q];
        }
    #pragma unroll
    for (int u = 0; u < 8; ++u) H[i * 256 + kb * 64 + c0 + u] = c[u];
    __syncthreads();                     // H complete

    // H -> M pivot rows (early: global writes drain under the update phase)
    #pragma unroll
    for (int rep = 0; rep < 16; ++rep) {
        int idx = rep * 512 + tid;
        int row = idx >> 7, col2 = idx & 127;
        *(double2*)&M[(size_t)(kb * 64 + row) * S + 2 * col2] =
            *(const double2*)&H[row * 256 + 2 * col2];
    }

    // ---- phase 3: update. interior RMW M -= F*H ; pivot cols <- -F*Pinv. Two 96-row halves.
    double* FT = SCR;                    // FT[kk][lr] = F[half*96+lr][ck*16+kk]  [16][194]
    #pragma unroll
    for (int half = 0; half < 2; ++half) {
        double2 acc[6][4];
        #pragma unroll
        for (int q = 0; q < 6; ++q)
            #pragma unroll
            for (int w = 0; w < 4; ++w) acc[q][w] = double2{0.0, 0.0};

        #pragma unroll
        for (int ck = 0; ck < 4; ++ck) {
            __syncthreads();             // prior SCR reads done
            #pragma unroll
            for (int rep = 0; rep < 3; ++rep) {
                int idx = rep * 512 + tid;
                int kk = idx & 15, lr = idx >> 4;    // lr 0..95
                FT[kk * 194 + lr] = fst[(half * 4 + ck) * 3 + rep];
            }
            __syncthreads();
            for (int kk = 0; kk < 16; ++kk) {
                int kr = ck * 16 + kk;
                double2 f01 = *(const double2*)&FT[kk * 194 + 6 * ty];
                double2 f23 = *(const double2*)&FT[kk * 194 + 6 * ty + 2];
                double2 f45 = *(const double2*)&FT[kk * 194 + 6 * ty + 4];
                #pragma unroll
                for (int w = 0; w < 4; ++w) {
                    double2 h = *(const double2*)&H[kr * 256 + 2 * tx + 64 * w];
                    acc[0][w].x = fma(f01.x, h.x, acc[0][w].x); acc[0][w].y = fma(f01.x, h.y, acc[0][w].y);
                    acc[1][w].x = fma(f01.y, h.x, acc[1][w].x); acc[1][w].y = fma(f01.y, h.y, acc[1][w].y);
                    acc[2][w].x = fma(f23.x, h.x, acc[2][w].x); acc[2][w].y = fma(f23.x, h.y, acc[2][w].y);
                    acc[3][w].x = fma(f23.y, h.x, acc[3][w].x); acc[3][w].y = fma(f23.y, h.y, acc[3][w].y);
                    acc[4][w].x = fma(f45.x, h.x, acc[4][w].x); acc[4][w].y = fma(f45.x, h.y, acc[4][w].y);
                    acc[5][w].x = fma(f45.y, h.x, acc[5][w].x); acc[5][w].y = fma(f45.y, h.y, acc[5][w].y);
                }
            }
        }
        // epilogue: own rows only (all F for this half already in fst registers)
        #pragma unroll
        for (int q = 0; q < 6; ++q) {
            size_t row = (size_t)rowmap(half * 96 + 6 * ty + q, kb) * S;
            #pragma unroll
            for (int w = 0; w < 4; ++w) {
                int j0 = 2 * tx + 64 * w;
                if (w == kb) {
                    *(double2*)&M[row + j0] = double2{-acc[q][w].x, -acc[q][w].y};
                } else {
                    double2 old = *(const double2*)&M[row + j0];
                    *(double2*)&M[row + j0] = double2{old.x - acc[q][w].x, old.y - acc[q][w].y};
                }
            }
        }
    }
}

// ---------------- kernel 4a: transpose X -> d_out (f32) at shifted positions + diag ---------
__global__ __launch_bounds__(256) void k_xt(const double* __restrict__ Mg,
                                            float* __restrict__ outF,
                                            double* __restrict__ Dg) {
    int b = blockIdx.y, t = blockIdx.x;
    int r = t & 3, c = t >> 2;
    const double* M = Mg + (size_t)b * S * S;
    __shared__ float L[64][65];
    int tid = threadIdx.x;
    int cc = tid & 63;
    #pragma unroll
    for (int rep = 0; rep < 16; ++rep) {
        int rr = rep * 4 + (tid >> 6);
        L[rr][cc] = (float)M[(size_t)(64 * r + rr) * S + 64 * c + cc];
    }
    if (r == c && tid < 64)
        Dg[(size_t)b * S + 64 * r + tid] = M[(size_t)(64 * r + tid) * S + 64 * r + tid];
    __syncthreads();
    int pp = tid & 63;
    #pragma unroll
    for (int rep = 0; rep < 16; ++rep) {
        int qq = rep * 4 + (tid >> 6);
        int orow = 64 * c + qq + 1, ocol = 64 * r + pp + 1;
        if (orow < 256 && ocol < 256)
            outF[((size_t)b * S + orow) * S + ocol] = L[pp][qq];   // = X[64r+pp][64c+qq]
    }
}

// ---------------- kernel 4b: elementwise in-place epilogue (float4) -------------------------
__global__ __launch_bounds__(256) void k_epi2(const float* __restrict__ sc,
                                              const double* __restrict__ Dg,
                                              const double* __restrict__ mb,
                                              const int* __restrict__ nb,
                                              float* __restrict__ out) {
    int b = blockIdx.y;
    int idx4 = blockIdx.x * 256 + threadIdx.x;    // 0..16383
    int i = idx4 >> 6;                            // row (wave-uniform)
    int jq = idx4 & 63;
    int n = nb[b];
    float m = (float)mb[b];
    size_t base = ((size_t)b * S + i) * S + 4 * jq;
    float4 xf = *(const float4*)(out + base);     // XFs[i][4jq..] = X[j-1][i-1]
    float4 s4 = *(const float4*)(sc + base);
    double dg = (i >= 1) ? Dg[(size_t)b * S + i - 1] : 0.0;
    float xfa[4] = {xf.x, xf.y, xf.z, xf.w};
    float sa[4]  = {s4.x, s4.y, s4.z, s4.w};
    float ra[4];
    #pragma unroll
    for (int comp = 0; comp < 4; ++comp) {
        int j = 4 * jq + comp;
        float v = 0.0f;
        if (i >= 1 && i <= n && j <= n) {
            double A = (double)expf(sa[comp] - m);
            double sub = (j >= 1) ? (double)xfa[comp] : 0.0;
            v = (float)(A * (dg - sub));
        }
        ra[comp] = v;
    }
    *(float4*)(out + base) = float4{ra[0], ra[1], ra[2], ra[3]};
}

// ---------------- launcher ----------------
extern "C" void kernel_launch(void* const* d_in, const int* in_sizes, int n_in,
                              void* d_out, int out_size, void* d_ws, size_t ws_size,
                              hipStream_t stream) {
    (void)in_sizes; (void)n_in; (void)out_size; (void)ws_size;
    const float* sc = (const float*)d_in[0];
    const unsigned char* mk = (const unsigned char*)d_in[1];
    double* ws = (double*)d_ws;

    double* M  = ws;                                 // B*256*256
    double* mb = M + (size_t)BB * S * S;             // B doubles
    int*    nb = (int*)(mb + BB);                    // B ints
    double* Dg = mb + 2 * BB;                        // B*256 doubles
    float*  partial = (float*)Dg;                    // aliases Dg (consumed before Dg written)
    float*  out = (float*)d_out;

    k_max<<<dim3(8, BB), 256, 0, stream>>>(sc, partial);
    k_n<<<BB, 256, 0, stream>>>(mk, partial, mb, nb);
    k_build<<<dim3(64, BB), 256, 0, stream>>>(sc, mb, nb, M);
    for (int kb = 0; kb < 4; ++kb)
        k_step<<<BB, 512, 0, stream>>>(M, kb);
    k_xt<<<dim3(16, BB), 256, 0, stream>>>(M, out, Dg);
    k_epi2<<<dim3(64, BB), 256, 0, stream>>>(sc, Dg, mb, nb, out);
}